// Round 4
// baseline (386.405 us; speedup 1.0000x reference)
//
#include <hip/hip_runtime.h>
#include <hip/hip_bf16.h>

typedef __bf16 bf16_t;
typedef bf16_t bf16x8 __attribute__((ext_vector_type(8)));
typedef bf16_t bf16x4 __attribute__((ext_vector_type(4)));
typedef float  f32x4  __attribute__((ext_vector_type(4)));

#define BK 64   // one K-tile; a row is 8 chunks of 8 bf16 (16B each)

enum { EPI_NONE = 0, EPI_THRESH = 1, EPI_BIAS = 2 };

__device__ __forceinline__ void memfence() { asm volatile("" ::: "memory"); }
__device__ __forceinline__ void blockbar() {
    memfence(); __builtin_amdgcn_s_barrier(); memfence();
}

#define GLD16(src, dst) __builtin_amdgcn_global_load_lds( \
    (const __attribute__((address_space(1))) void*)(src), \
    (__attribute__((address_space(3))) void*)(dst), 16, 0, 0)

// ============================================================================
// gemm_h_tile: C_bf16 = EPI( A_fp32 @ B_fp32^T ), 256x128 tile, 8 waves of
// 64x64. fp32 operands are reg-staged (global->reg->cvt->swizzled ds_write),
// eliminating the separate conversion dispatch (T14 issue-early/write-late):
//   phase 1: issue 12 f32x4 loads for tile t+1; ds_read frags; bar; MFMA
//   phase 2: ds_read frags; vmcnt(0); cvt+ds_write -> buf^1; lgkm(0); bar; MFMA
// LDS layout: unit(row,chunk) = row*8 + (chunk ^ (row&7)), same XOR swizzle
// as the gload_lds path (0 measured bank conflicts); write side applies the
// XOR on the ds_write address, read side identical to before.
// STRIDED_B=1: B operand is W^T, i.e. B[n,k] = W[k,n] (scalar strided loads;
// only used by the 18 tiny Wc blocks, W is L2-resident).
// ============================================================================
template <int EPI, int STRIDED_B>
__device__ __forceinline__
void gemm_h_tile(const float* __restrict__ A, const float* __restrict__ B,
                 bf16_t* __restrict__ C, int m0, int n0, int N, int K,
                 bf16_t* __restrict__ As, bf16_t* __restrict__ Bs)
{
    const int lane = threadIdx.x & 63;
    const int wave = threadIdx.x >> 6;   // 0..7
    const int wm = wave >> 1;            // 0..3 : 64-row band
    const int wn = wave & 1;             // 0..1 : 64-col band

    const int fm  = lane & 15;
    const int ql  = lane >> 4;
    const int fsw = fm & 7;

    const int NT = K / BK;               // 12

    // --- staging addressing: per tile, wave stages 32 A-rows + 16 B-rows.
    const int arow = wave * 32 + (lane >> 1);   // A row in tile [0,256)
    const int acb  = (lane & 1) * 4;            // A 8-elem chunk base
    const float* pa = A + (size_t)(m0 + arow) * K + acb * 8;
    const int brow = wave * 16 + (lane >> 2);   // B row in tile [0,128)
    const int bcb  = (lane & 3) * 2;            // B 8-elem chunk base
    const float* pb = STRIDED_B ? (B + (size_t)(n0 + brow))
                                : (B + (size_t)(n0 + brow) * K + bcb * 8);

    f32x4 ar[8]; f32x4 brv[4]; float bsv[16];

#define H_ISSUE(tt) do {                                                     \
    _Pragma("unroll") for (int i_ = 0; i_ < 8; ++i_)                         \
        ar[i_] = *(const f32x4*)(pa + (size_t)(tt) * BK + i_ * 4);           \
    if (!STRIDED_B) {                                                        \
        _Pragma("unroll") for (int i_ = 0; i_ < 4; ++i_)                     \
            brv[i_] = *(const f32x4*)(pb + (size_t)(tt) * BK + i_ * 4);      \
    } else {                                                                 \
        _Pragma("unroll") for (int i_ = 0; i_ < 16; ++i_)                    \
            bsv[i_] = pb[(size_t)((tt) * BK + bcb * 8 + i_) * K];            \
    } } while (0)

#define H_WRITE(Ad, Bd) do {                                                 \
    _Pragma("unroll") for (int c_ = 0; c_ < 4; ++c_) {                       \
        bf16x8 w_;                                                           \
        _Pragma("unroll") for (int e_ = 0; e_ < 4; ++e_) {                   \
            w_[e_]     = (bf16_t)ar[c_ * 2][e_];                             \
            w_[4 + e_] = (bf16_t)ar[c_ * 2 + 1][e_];                         \
        }                                                                    \
        *(bf16x8*)((Ad) + (size_t)(arow * 8 + ((acb + c_) ^ (arow & 7))) * 8)\
            = w_;                                                            \
    }                                                                        \
    _Pragma("unroll") for (int c_ = 0; c_ < 2; ++c_) {                       \
        bf16x8 w_;                                                           \
        if (!STRIDED_B) {                                                    \
            _Pragma("unroll") for (int e_ = 0; e_ < 4; ++e_) {               \
                w_[e_]     = (bf16_t)brv[c_ * 2][e_];                        \
                w_[4 + e_] = (bf16_t)brv[c_ * 2 + 1][e_];                    \
            }                                                                \
        } else {                                                             \
            _Pragma("unroll") for (int e_ = 0; e_ < 8; ++e_)                 \
                w_[e_] = (bf16_t)bsv[c_ * 8 + e_];                           \
        }                                                                    \
        *(bf16x8*)((Bd) + (size_t)(brow * 8 + ((bcb + c_) ^ (brow & 7))) * 8)\
            = w_;                                                            \
    } } while (0)

    f32x4 acc[4][4];
#pragma unroll
    for (int i = 0; i < 4; ++i)
#pragma unroll
        for (int j = 0; j < 4; ++j) acc[i][j] = (f32x4){0.f, 0.f, 0.f, 0.f};

    // prologue: tile 0 -> buf0
    H_ISSUE(0);
    asm volatile("s_waitcnt vmcnt(0)" ::: "memory");
    H_WRITE(As, Bs);
    asm volatile("s_waitcnt lgkmcnt(0)" ::: "memory");
    blockbar();

    for (int t = 0; t < NT; ++t) {
        const int cur = t & 1;
        const bf16_t* __restrict__ Ab = As + cur * (256 * BK);
        const bf16_t* __restrict__ Bb = Bs + cur * (128 * BK);
        bf16_t* Asd = As + (cur ^ 1) * (256 * BK);
        bf16_t* Bsd = Bs + (cur ^ 1) * (128 * BK);
        const bool stage = (t + 1 < NT);

        bf16x8 af[4][2], bfr[2][2];

        // ---- phase 1: issue next-tile loads; frag reads; MFMA j=0,1 ----
        if (stage) H_ISSUE(t + 1);
#pragma unroll
        for (int i = 0; i < 4; ++i) {
            const int row = wm * 64 + i * 16 + fm;
#pragma unroll
            for (int kk = 0; kk < 2; ++kk)
                af[i][kk] = *(const bf16x8*)(Ab + (size_t)(row * 8 + ((kk * 4 + ql) ^ fsw)) * 8);
        }
#pragma unroll
        for (int j = 0; j < 2; ++j) {
            const int row = wn * 64 + j * 16 + fm;
#pragma unroll
            for (int kk = 0; kk < 2; ++kk)
                bfr[j][kk] = *(const bf16x8*)(Bb + (size_t)(row * 8 + ((kk * 4 + ql) ^ fsw)) * 8);
        }
        blockbar();
        asm volatile("s_waitcnt lgkmcnt(0)" ::: "memory");
        __builtin_amdgcn_sched_barrier(0);
        __builtin_amdgcn_s_setprio(1);
#pragma unroll
        for (int i = 0; i < 4; ++i)
#pragma unroll
            for (int j = 0; j < 2; ++j)
#pragma unroll
                for (int kk = 0; kk < 2; ++kk)
                    acc[i][j] = __builtin_amdgcn_mfma_f32_16x16x32_bf16(
                        af[i][kk], bfr[j][kk], acc[i][j], 0, 0, 0);
        __builtin_amdgcn_s_setprio(0);
        blockbar();

        // ---- phase 2: frag reads; cvt+write tile t+1; MFMA j=2,3 ----
#pragma unroll
        for (int j = 0; j < 2; ++j) {
            const int row = wn * 64 + (j + 2) * 16 + fm;
#pragma unroll
            for (int kk = 0; kk < 2; ++kk)
                bfr[j][kk] = *(const bf16x8*)(Bb + (size_t)(row * 8 + ((kk * 4 + ql) ^ fsw)) * 8);
        }
        if (stage) {
            asm volatile("s_waitcnt vmcnt(0)" ::: "memory");
            H_WRITE(Asd, Bsd);
        }
        // own frag-reads AND staging writes retired before the barrier so
        // every wave's writes are visible to all after crossing it
        asm volatile("s_waitcnt lgkmcnt(0)" ::: "memory");
        blockbar();
        __builtin_amdgcn_sched_barrier(0);
        __builtin_amdgcn_s_setprio(1);
#pragma unroll
        for (int i = 0; i < 4; ++i)
#pragma unroll
            for (int j = 0; j < 2; ++j)
#pragma unroll
                for (int kk = 0; kk < 2; ++kk)
                    acc[i][j + 2] = __builtin_amdgcn_mfma_f32_16x16x32_bf16(
                        af[i][kk], bfr[j][kk], acc[i][j + 2], 0, 0, 0);
        __builtin_amdgcn_s_setprio(0);
        blockbar();
    }

    // epilogue: C/D layout col=lane&15, row=ql*4+r
#pragma unroll
    for (int i = 0; i < 4; ++i) {
#pragma unroll
        for (int j = 0; j < 4; ++j) {
            const int col = n0 + wn * 64 + j * 16 + fm;
#pragma unroll
            for (int r = 0; r < 4; ++r) {
                const int row = m0 + wm * 64 + i * 16 + ql * 4 + r;
                float v = acc[i][j][r];
                if (EPI == EPI_THRESH) v = (fabsf(v) > 1e-3f) ? v : 0.f;
                C[(size_t)row * N + col] = (bf16_t)v;
            }
        }
    }
#undef H_ISSUE
#undef H_WRITE
}

// ============================================================================
// gemm_out tile (unchanged from round 3): 256x256, 8 waves of 128x64,
// bf16 operands via global_load_lds with global-side XOR pre-swizzle,
// 4 phases/K-tile, issue-early staging, fp32+bias store.
// ============================================================================
__device__ __forceinline__
void gemm_o_tile(const bf16_t* __restrict__ A, const bf16_t* __restrict__ B,
                 float* __restrict__ C, const float* __restrict__ bias,
                 int m0, int n0, int N, int K,
                 bf16_t* __restrict__ As, bf16_t* __restrict__ Bs)
{
    const int lane = threadIdx.x & 63;
    const int wave = threadIdx.x >> 6;   // 0..7
    const int wm = wave >> 2;            // 0..1 : 128-row band of A
    const int wn = wave & 3;             // 0..3 : 64-col band of B

    const int fm  = lane & 15;
    const int ql  = lane >> 4;
    const int fsw = fm & 7;

    const int NT = K / BK;               // 12

    const int choff = ((lane & 7) ^ ((lane >> 3) & 7)) * 8;
    const bf16_t* pA[2]; const bf16_t* pB[2];
    int sd[2];
#pragma unroll
    for (int l = 0; l < 2; ++l) {
        const int r = (wave * 2 + l) * 8 + (lane >> 3);
        pA[l] = A + (size_t)(m0 + r) * K + choff;
        pB[l] = B + (size_t)(n0 + r) * K + choff;
        sd[l] = (wave * 2 + l) * 64;
    }

#define STAGE_TILE(tt, Ad, Bd) do {                                          \
    _Pragma("unroll") for (int h_ = 0; h_ < 2; ++h_)                         \
    _Pragma("unroll") for (int l_ = 0; l_ < 2; ++l_) {                       \
        GLD16(pA[l_] + (size_t)h_ * 128 * K + (size_t)(tt) * BK,             \
              (Ad) + (size_t)(h_ * 1024 + sd[l_]) * 8);                      \
        GLD16(pB[l_] + (size_t)h_ * 128 * K + (size_t)(tt) * BK,             \
              (Bd) + (size_t)(h_ * 1024 + sd[l_]) * 8);                      \
    } } while (0)

#define LOAD_A(mh) do {                                                      \
    _Pragma("unroll") for (int i_ = 0; i_ < 4; ++i_)                         \
    _Pragma("unroll") for (int k_ = 0; k_ < 2; ++k_)                         \
        af[i_][k_] = *(const bf16x8*)(Ab + (size_t)(                         \
            (wm * 128 + (mh) * 64 + i_ * 16 + fm) * 8 +                      \
            ((k_ * 4 + ql) ^ fsw)) * 8); } while (0)

#define LOAD_B(nh) do {                                                      \
    _Pragma("unroll") for (int j_ = 0; j_ < 2; ++j_)                         \
    _Pragma("unroll") for (int k_ = 0; k_ < 2; ++k_)                         \
        bfx[j_][k_] = *(const bf16x8*)(Bb + (size_t)(                        \
            (wn * 64 + (nh) * 32 + j_ * 16 + fm) * 8 +                       \
            ((k_ * 4 + ql) ^ fsw)) * 8); } while (0)

#define MFMA_Q(mh, nh) do {                                                  \
    _Pragma("unroll") for (int i_ = 0; i_ < 4; ++i_)                         \
    _Pragma("unroll") for (int j_ = 0; j_ < 2; ++j_)                         \
    _Pragma("unroll") for (int k_ = 0; k_ < 2; ++k_)                         \
        acc[(mh) * 4 + i_][(nh) * 2 + j_] =                                  \
            __builtin_amdgcn_mfma_f32_16x16x32_bf16(                         \
                af[i_][k_], bfx[j_][k_],                                     \
                acc[(mh) * 4 + i_][(nh) * 2 + j_], 0, 0, 0); } while (0)

#define PHASE_TAIL(mh, nh) do {                                              \
    blockbar();                                                              \
    asm volatile("s_waitcnt lgkmcnt(0)" ::: "memory");                       \
    __builtin_amdgcn_sched_barrier(0);                                       \
    __builtin_amdgcn_s_setprio(1);                                           \
    MFMA_Q(mh, nh);                                                          \
    __builtin_amdgcn_s_setprio(0);                                           \
    blockbar(); } while (0)

    f32x4 acc[8][4];
#pragma unroll
    for (int i = 0; i < 8; ++i)
#pragma unroll
        for (int j = 0; j < 4; ++j) acc[i][j] = (f32x4){0.f, 0.f, 0.f, 0.f};

    STAGE_TILE(0, As, Bs);
    asm volatile("s_waitcnt vmcnt(0)" ::: "memory");
    blockbar();

    for (int t = 0; t < NT; ++t) {
        const int cur = t & 1;
        const bf16_t* __restrict__ Ab = As + cur * (256 * BK);
        const bf16_t* __restrict__ Bb = Bs + cur * (256 * BK);
        bf16_t* Asd = As + (cur ^ 1) * (256 * BK);
        bf16_t* Bsd = Bs + (cur ^ 1) * (256 * BK);

        bf16x8 af[4][2], bfx[2][2];

        LOAD_A(0); LOAD_B(0);
        if (t + 1 < NT) STAGE_TILE(t + 1, Asd, Bsd);
        PHASE_TAIL(0, 0);

        LOAD_B(1);
        PHASE_TAIL(0, 1);

        LOAD_A(1);
        PHASE_TAIL(1, 1);

        LOAD_B(0);
        asm volatile("s_waitcnt vmcnt(0)" ::: "memory");
        PHASE_TAIL(1, 0);
    }

#pragma unroll
    for (int mi = 0; mi < 8; ++mi) {
#pragma unroll
        for (int ni = 0; ni < 4; ++ni) {
            const int col = n0 + wn * 64 + ni * 16 + fm;
            const float bv = bias[col];
#pragma unroll
            for (int r = 0; r < 4; ++r) {
                const int row = m0 + wm * 128 + mi * 16 + ql * 4 + r;
                C[(size_t)row * N + col] = acc[mi][ni][r] + bv;
            }
        }
    }
#undef STAGE_TILE
#undef LOAD_A
#undef LOAD_B
#undef MFMA_Q
#undef PHASE_TAIL
}

// dispatch 1: h = thresh(x_f32 @ U_f32^T) [blocks 0..767, bijective XCD
// swizzle, 768%8==0, 3 exact rounds at 1 block/CU] and Wc = VT @ W
// [blocks 768..785, B = W^T via strided loads]. No prep dispatch needed.
__global__ __launch_bounds__(512, 2)
void gemm_h_wc(const float* __restrict__ x, const float* __restrict__ U,
               bf16_t* __restrict__ h,
               const float* __restrict__ VT, const float* __restrict__ w,
               bf16_t* __restrict__ Wc)
{
    __shared__ __align__(16) bf16_t As[2 * 256 * BK];   // 64 KiB
    __shared__ __align__(16) bf16_t Bs[2 * 128 * BK];   // 32 KiB
    const int b = blockIdx.x;
    if (b < 768) {
        const int L = (b & 7) * 96 + (b >> 3);
        gemm_h_tile<EPI_THRESH, 0>(x, U, h,
                                   (L / 6) * 256, (L % 6) * 128, 768, 768, As, Bs);
    } else {
        const int b2 = b - 768;                          // 0..17: 3x6 tiles
        gemm_h_tile<EPI_NONE, 1>(VT, w, Wc,
                                 (b2 / 6) * 256, (b2 % 6) * 128, 768, 768, As, Bs);
    }
}

// dispatch 2: out = h @ Wc^T + bias (fp32 store)
__global__ __launch_bounds__(512, 2)
void gemm_out(const bf16_t* __restrict__ h, const bf16_t* __restrict__ Wc,
              float* __restrict__ out, const float* __restrict__ bias)
{
    __shared__ __align__(16) bf16_t As[2 * 256 * BK];
    __shared__ __align__(16) bf16_t Bs[2 * 256 * BK];
    const int b = blockIdx.x;
    const int L = (b & 7) * 48 + (b >> 3);
    gemm_o_tile(h, Wc, out, bias,
                (L / 3) * 256, (L % 3) * 256, 768, 768, As, Bs);
}

extern "C" void kernel_launch(void* const* d_in, const int* in_sizes, int n_in,
                              void* d_out, int out_size, void* d_ws, size_t ws_size,
                              hipStream_t stream)
{
    const float* x    = (const float*)d_in[0];   // (8,4096,768) fp32
    const float* w    = (const float*)d_in[1];   // (768,768) fp32
    const float* bias = (const float*)d_in[2];   // (768,) fp32
    const float* U    = (const float*)d_in[3];   // (768,768) fp32
    const float* VT   = (const float*)d_in[4];   // (768,768) fp32
    float* out = (float*)d_out;                  // (8,4096,768) fp32

    const int D = 768;
    const int M = 8 * 4096;                      // 32768
    const size_t MD = (size_t)M * D;

    char* ws = (char*)d_ws;
    bf16_t* h  = (bf16_t*)ws;                    // MD bf16
    bf16_t* Wc = (bf16_t*)(ws + MD * 2);         // D*D bf16: VT@W

    // 1) h = thresh(x @ U^T) with fused fp32->bf16 staging + Wc = VT@W
    gemm_h_wc<<<768 + 18, 512, 0, stream>>>(x, U, h, VT, w, Wc);
    // 2) out = h @ Wc^T + bias  (== ((h @ W^T) @ VT^T) + bias)
    gemm_out<<<384, 512, 0, stream>>>(h, Wc, out, bias);
}

// Round 5
// 295.405 us; speedup vs baseline: 1.3081x; 1.3081x over previous
//
#include <hip/hip_runtime.h>
#include <hip/hip_bf16.h>

typedef __bf16 bf16_t;
typedef bf16_t bf16x8 __attribute__((ext_vector_type(8)));
typedef bf16_t bf16x4 __attribute__((ext_vector_type(4)));
typedef float  f32x4  __attribute__((ext_vector_type(4)));

#define BM 256
#define BN 128
#define BK 64   // one K-tile; a row is 8 chunks of 8 bf16 (16B each)

enum { EPI_NONE = 0, EPI_THRESH = 1, EPI_BIAS = 2 };

__device__ __forceinline__ void memfence() { asm volatile("" ::: "memory"); }
// raw barrier (NO vmcnt drain) with compiler memory fences so LDS ops can't
// be moved across it by the optimizer.
__device__ __forceinline__ void blockbar() {
    memfence(); __builtin_amdgcn_s_barrier(); memfence();
}

#define GLD16(src, dst) __builtin_amdgcn_global_load_lds( \
    (const __attribute__((address_space(1))) void*)(src), \
    (__attribute__((address_space(3))) void*)(dst), 16, 0, 0)

// 256x128 tile, BK=64, 512 threads = 8 waves (4M x 2N), per-wave C = 64x64.
// 3-deep LDS pipeline (144 KiB): compute tile t from buf[t%3] while tile t+1
// is fully in flight and tile t+2 streams into buf[(t+2)%3] -> steady-state
// s_waitcnt vmcnt(6), never 0 in the main loop (T3+T4). Measured (round 2):
// 70 us, MfmaUtil 21.5%, 0 bank conflicts. This is the session-best h-GEMM.
template <int EPI, typename CT>
__device__ __forceinline__
void gemm_tile(const bf16_t* __restrict__ A, const bf16_t* __restrict__ B,
               CT* __restrict__ C, const float* __restrict__ bias,
               int m0, int n0, int N, int K,
               bf16_t* __restrict__ As, bf16_t* __restrict__ Bs)
{
    const int lane = threadIdx.x & 63;
    const int wave = threadIdx.x >> 6;   // 0..7
    const int wm = wave >> 1;            // 0..3: 64-row band of A
    const int wn = wave & 1;             // 0..1: 64-col band of B

    const int fm  = lane & 15;
    const int q   = lane >> 4;
    const int fsw = fm & 7;

    const int NT = K / BK;               // 12 for K=768

    // staging: each wave issues 6 global_load_lds per K-tile (4 A + 2 B),
    // each covering 64 lanes x 16B = 1 KiB = 8 rows. Global-side XOR
    // pre-swizzle (chunk ^= row&7) keeps LDS linear for the HW constraint.
    const bf16_t* gsrc[6];
    int ldst[6];
#pragma unroll
    for (int s = 0; s < 6; ++s) {
        const int g = wave + 8 * s;       // 0..47
        if (s < 4) {                      // A: units [0,2048) over 256 rows
            const int u = g * 64 + lane;
            const int row = u >> 3;
            const int ch  = (u & 7) ^ (row & 7);
            gsrc[s] = A + (size_t)(m0 + row) * K + ch * 8;
            ldst[s] = g * 512;
        } else {                          // B: units [0,1024) over 128 rows
            const int u = (g - 32) * 64 + lane;
            const int row = u >> 3;
            const int ch  = (u & 7) ^ (row & 7);
            gsrc[s] = B + (size_t)(n0 + row) * K + ch * 8;
            ldst[s] = (g - 32) * 512;
        }
    }

    f32x4 acc[4][4];
#pragma unroll
    for (int i = 0; i < 4; ++i)
#pragma unroll
        for (int j = 0; j < 4; ++j) acc[i][j] = (f32x4){0.f, 0.f, 0.f, 0.f};

    // prologue: stage tile 0 -> buf0, tile 1 -> buf1; wait tile0 only.
#pragma unroll
    for (int s = 0; s < 6; ++s) {
        GLD16(gsrc[s], (s < 4 ? As : Bs) + ldst[s]);
        gsrc[s] += BK;
    }
#pragma unroll
    for (int s = 0; s < 6; ++s) {
        GLD16(gsrc[s], (s < 4 ? As + 256 * 64 : Bs + 128 * 64) + ldst[s]);
        gsrc[s] += BK;
    }
    asm volatile("s_waitcnt vmcnt(6)" ::: "memory");   // tile0 landed
    blockbar();

    int bc = 0;                                        // compute buffer
    for (int t = 0; t < NT; ++t) {
        const bf16_t* __restrict__ Ab = As + bc * (256 * 64);
        const bf16_t* __restrict__ Bb = Bs + bc * (128 * 64);
        const int bs2 = (bc >= 1) ? bc - 1 : 2;        // (bc+2)%3
        bf16_t* Asd = As + bs2 * (256 * 64);
        bf16_t* Bsd = Bs + bs2 * (128 * 64);
        const bool do_stage = (t + 2 < NT);

        bf16x8 af[4][2], bfr[2][2];

        // ---------- phase 1: 12 ds_read + 3 stage + 16 MFMA ----------
#pragma unroll
        for (int i = 0; i < 4; ++i) {
            const int row = wm * 64 + i * 16 + fm;
#pragma unroll
            for (int kk = 0; kk < 2; ++kk)
                af[i][kk] = *(const bf16x8*)(Ab + (size_t)(row * 8 + ((kk * 4 + q) ^ fsw)) * 8);
        }
#pragma unroll
        for (int j = 0; j < 2; ++j) {
            const int row = wn * 64 + j * 16 + fm;
#pragma unroll
            for (int kk = 0; kk < 2; ++kk)
                bfr[j][kk] = *(const bf16x8*)(Bb + (size_t)(row * 8 + ((kk * 4 + q) ^ fsw)) * 8);
        }
        if (do_stage) {
            GLD16(gsrc[0], Asd + ldst[0]); gsrc[0] += BK;
            GLD16(gsrc[1], Asd + ldst[1]); gsrc[1] += BK;
            GLD16(gsrc[4], Bsd + ldst[4]); gsrc[4] += BK;
        }
        blockbar();
        __builtin_amdgcn_s_setprio(1);
#pragma unroll
        for (int i = 0; i < 4; ++i)
#pragma unroll
            for (int j = 0; j < 2; ++j)
#pragma unroll
                for (int kk = 0; kk < 2; ++kk)
                    acc[i][j] = __builtin_amdgcn_mfma_f32_16x16x32_bf16(
                        af[i][kk], bfr[j][kk], acc[i][j], 0, 0, 0);
        __builtin_amdgcn_s_setprio(0);
        blockbar();

        // ---------- phase 2: 4 ds_read + 3 stage + 16 MFMA ----------
#pragma unroll
        for (int j = 0; j < 2; ++j) {
            const int row = wn * 64 + (j + 2) * 16 + fm;
#pragma unroll
            for (int kk = 0; kk < 2; ++kk)
                bfr[j][kk] = *(const bf16x8*)(Bb + (size_t)(row * 8 + ((kk * 4 + q) ^ fsw)) * 8);
        }
        if (do_stage) {
            GLD16(gsrc[2], Asd + ldst[2]); gsrc[2] += BK;
            GLD16(gsrc[3], Asd + ldst[3]); gsrc[3] += BK;
            GLD16(gsrc[5], Bsd + ldst[5]); gsrc[5] += BK;
        }
        blockbar();
        __builtin_amdgcn_s_setprio(1);
#pragma unroll
        for (int i = 0; i < 4; ++i)
#pragma unroll
            for (int j = 0; j < 2; ++j)
#pragma unroll
                for (int kk = 0; kk < 2; ++kk)
                    acc[i][j + 2] = __builtin_amdgcn_mfma_f32_16x16x32_bf16(
                        af[i][kk], bfr[j][kk], acc[i][j + 2], 0, 0, 0);
        __builtin_amdgcn_s_setprio(0);

        if (t < NT - 1) {
            // all of this wave's ds_reads must retire before staging may
            // overwrite a rotated-out buffer behind the barrier
            asm volatile("s_waitcnt lgkmcnt(0)" ::: "memory");
            if (do_stage) asm volatile("s_waitcnt vmcnt(6)" ::: "memory"); // tile t+1 landed
            else          asm volatile("s_waitcnt vmcnt(0)" ::: "memory"); // drain tail
            blockbar();
        }
        bc = (bc >= 2) ? 0 : bc + 1;
    }

    // epilogue: C/D layout col=lane&15, row=q*4+r
#pragma unroll
    for (int i = 0; i < 4; ++i) {
#pragma unroll
        for (int j = 0; j < 4; ++j) {
            const int col = n0 + wn * 64 + j * 16 + fm;
            float bv = 0.f;
            if (EPI == EPI_BIAS) bv = bias[col];
#pragma unroll
            for (int r = 0; r < 4; ++r) {
                const int row = m0 + wm * 64 + i * 16 + q * 4 + r;
                float v = acc[i][j][r];
                if (EPI == EPI_THRESH) v = (fabsf(v) > 1e-3f) ? v : 0.f;
                if (EPI == EPI_BIAS) v += bv;
                C[(size_t)row * N + col] = (CT)v;
            }
        }
    }
}

// dispatch 2: h = thresh(xb @ Ub^T) [blocks 0..767, XCD-swizzled; 768%8==0 so
// the simple bijective swizzle is valid] and Wc = VTb @ Wt^T [blocks 768..785].
__global__ __launch_bounds__(512, 2)
void gemm_h_wc(const bf16_t* __restrict__ xb, const bf16_t* __restrict__ Ub,
               bf16_t* __restrict__ h,
               const bf16_t* __restrict__ VTb, const bf16_t* __restrict__ Wt,
               bf16_t* __restrict__ Wc)
{
    __shared__ __align__(16) bf16_t As[3 * 256 * 64];   // 96 KiB
    __shared__ __align__(16) bf16_t Bs[3 * 128 * 64];   // 48 KiB
    const int b = blockIdx.x;
    if (b < 768) {
        const int L = (b & 7) * 96 + (b >> 3);          // XCD-contiguous tiles
        gemm_tile<EPI_THRESH, bf16_t>(xb, Ub, h, nullptr,
                                      (L / 6) * BM, (L % 6) * BN, 768, 768, As, Bs);
    } else {
        const int b2 = b - 768;                          // 0..17
        gemm_tile<EPI_NONE, bf16_t>(VTb, Wt, Wc, nullptr,
                                    (b2 / 6) * BM, (b2 % 6) * BN, 768, 768, As, Bs);
    }
}

// dispatch 3: out = h @ Wc^T + bias (fp32 store)
__global__ __launch_bounds__(512, 2)
void gemm_out(const bf16_t* __restrict__ h, const bf16_t* __restrict__ Wc,
              float* __restrict__ out, const float* __restrict__ bias)
{
    __shared__ __align__(16) bf16_t As[3 * 256 * 64];
    __shared__ __align__(16) bf16_t Bs[3 * 128 * 64];
    const int b = blockIdx.x;
    const int L = (b & 7) * 96 + (b >> 3);
    gemm_tile<EPI_BIAS, float>(h, Wc, out, bias,
                               (L / 6) * BM, (L % 6) * BN, 768, 768, As, Bs);
}

// dispatch 1: fp32->bf16 conversions + weight transpose. Vectorized: each
// thread moves 32B read / 16B write per cvt iteration (2 adjacent f32x4 ->
// one bf16x8 store), halving the cvt block count vs the previous prep.
// blocks [0,12288): x; [12288,12576): U; [12576,12864): VT; [12864,13440): w^T
__global__ __launch_bounds__(256)
void prep(const float* __restrict__ x, const float* __restrict__ U,
          const float* __restrict__ VT, const float* __restrict__ w,
          bf16_t* __restrict__ xb, bf16_t* __restrict__ Ub,
          bf16_t* __restrict__ VTb, bf16_t* __restrict__ Wt)
{
    __shared__ float tt[32][33];
    const int b = blockIdx.x;
    if (b < 12864) {
        const float* src; bf16_t* dst; size_t e;
        if (b < 12288)      { src = x;  dst = xb;  e = (size_t)b * 2048; }
        else if (b < 12576) { src = U;  dst = Ub;  e = (size_t)(b - 12288) * 2048; }
        else                { src = VT; dst = VTb; e = (size_t)(b - 12576) * 2048; }
        const size_t i = e + (size_t)threadIdx.x * 8;
        const f32x4 v0 = *(const f32x4*)(src + i);
        const f32x4 v1 = *(const f32x4*)(src + i + 4);
        bf16x8 o;
        o[0] = (bf16_t)v0[0]; o[1] = (bf16_t)v0[1];
        o[2] = (bf16_t)v0[2]; o[3] = (bf16_t)v0[3];
        o[4] = (bf16_t)v1[0]; o[5] = (bf16_t)v1[1];
        o[6] = (bf16_t)v1[2]; o[7] = (bf16_t)v1[3];
        *(bf16x8*)(dst + i) = o;
    } else {
        const int t = b - 12864;              // 0..575
        const int bx = (t % 24) * 32, by = (t / 24) * 32;
        const int tx = threadIdx.x & 31, ty = threadIdx.x >> 5;  // 32 x 8
#pragma unroll
        for (int i = 0; i < 32; i += 8)
            tt[ty + i][tx] = w[(size_t)(by + ty + i) * 768 + bx + tx];
        __syncthreads();
#pragma unroll
        for (int i = 0; i < 32; i += 8)
            Wt[(size_t)(bx + ty + i) * 768 + by + tx] = (bf16_t)tt[tx][ty + i];
    }
}

extern "C" void kernel_launch(void* const* d_in, const int* in_sizes, int n_in,
                              void* d_out, int out_size, void* d_ws, size_t ws_size,
                              hipStream_t stream)
{
    const float* x    = (const float*)d_in[0];   // (8,4096,768) fp32
    const float* w    = (const float*)d_in[1];   // (768,768) fp32
    const float* bias = (const float*)d_in[2];   // (768,) fp32
    const float* U    = (const float*)d_in[3];   // (768,768) fp32
    const float* VT   = (const float*)d_in[4];   // (768,768) fp32
    float* out = (float*)d_out;                  // (8,4096,768) fp32

    const int D = 768;
    const int M = 8 * 4096;                      // 32768
    const size_t MD = (size_t)M * D;
    const size_t DD = (size_t)D * D;

    char* ws = (char*)d_ws;
    bf16_t* xb  = (bf16_t*)ws;                         // MD bf16
    bf16_t* h   = (bf16_t*)(ws + MD * 2);              // MD bf16
    bf16_t* Ub  = (bf16_t*)(ws + MD * 4);              // DD
    bf16_t* VTb = (bf16_t*)(ws + MD * 4 + DD * 2);     // DD
    bf16_t* Wt  = (bf16_t*)(ws + MD * 4 + DD * 4);     // DD: weight^T
    bf16_t* Wc  = (bf16_t*)(ws + MD * 4 + DD * 6);     // DD: VT@weight

    // 1) conversions + transpose fused (vectorized)
    prep<<<13440, 256, 0, stream>>>(x, U, VT, w, xb, Ub, VTb, Wt);
    // 2) h = thresh(xb @ Ub^T)  +  Wc = (VT @ weight) in the same dispatch
    gemm_h_wc<<<768 + 18, 512, 0, stream>>>(xb, Ub, h, VTb, Wt, Wc);
    // 3) out = h @ Wc^T + bias  (== ((h @ W^T) @ VT^T) + bias)
    gemm_out<<<768, 512, 0, stream>>>(h, Wc, out, bias);
}

// Round 6
// 277.957 us; speedup vs baseline: 1.3902x; 1.0628x over previous
//
#include <hip/hip_runtime.h>
#include <hip/hip_bf16.h>

typedef __bf16 bf16_t;
typedef bf16_t bf16x8 __attribute__((ext_vector_type(8)));
typedef bf16_t bf16x4 __attribute__((ext_vector_type(4)));
typedef float  f32x4  __attribute__((ext_vector_type(4)));

#define BM 256
#define BN 128
#define BK 32            // one K-tile; a row is 4 chunks of 8 bf16 (16B each)
#define ABUF (BM * BK)   // 8192 elems
#define BBUF (BN * BK)   // 4096 elems

enum { EPI_NONE = 0, EPI_THRESH = 1, EPI_BIAS = 2 };

__device__ __forceinline__ void memfence() { asm volatile("" ::: "memory"); }
__device__ __forceinline__ void blockbar() {
    memfence(); __builtin_amdgcn_s_barrier(); memfence();
}

#define GLD16(src, dst) __builtin_amdgcn_global_load_lds( \
    (const __attribute__((address_space(1))) void*)(src), \
    (__attribute__((address_space(3))) void*)(dst), 16, 0, 0)

// 256x128 tile, BK=32, 512 threads = 8 waves (4M x 2N), per-wave C = 64x64.
// KEY CHANGE vs prior rounds: 72 KiB LDS (3-deep x BK=32) -> 2 blocks/CU
// co-resident (__launch_bounds__(512,4) caps VGPR at 128). Every earlier
// variant ran 1 block/CU and plateaued at MfmaUtil ~21% with all pipes idle
// ~2/3 of the time: barrier stalls had nothing to fill them. Now the other
// block's waves fill them.
// Pipeline: tile t computes from buf[t%3] while t+1 is landed/in-flight and
// t+2 streams into buf[(t+2)%3]; steady-state s_waitcnt vmcnt(3) (3 loads/
// wave/tile: 2 A + 1 B), ONE barrier per K-tile (24 total).
// Swizzle (BK=32): unit(row,chunk) = row*4 + (chunk ^ ((row ^ row>>2) & 3)),
// applied on the GLOBAL side of global_load_lds (LDS dest stays linear,
// satisfying the wave-uniform-base + lane*16 rule). Verified: fragment
// ds_read_b128s land 2 lanes per 16B bank-slot (2-way = free).
template <int EPI, typename CT>
__device__ __forceinline__
void gemm_tile(const bf16_t* __restrict__ A, const bf16_t* __restrict__ B,
               CT* __restrict__ C, const float* __restrict__ bias,
               int m0, int n0, int N, int K,
               bf16_t* __restrict__ As, bf16_t* __restrict__ Bs)
{
    const int lane = threadIdx.x & 63;
    const int wave = threadIdx.x >> 6;   // 0..7
    const int wm = wave >> 1;            // 0..3: 64-row band of A
    const int wn = wave & 1;             // 0..1: 64-col band of B

    const int fm   = lane & 15;
    const int q    = lane >> 4;          // 0..3 = k-chunk of the fragment
    const int fsw2 = (fm ^ (fm >> 2)) & 3;

    const int NT = K / BK;               // 24 for K=768

    // --- staging: per K-tile each wave issues 3 global_load_lds
    // (2 A-slots + 1 B-slot), each 64 lanes x 16B = 1 KiB.
    // A: unit u = (wave*2+s)*64 + lane over 1024 units (256 rows x 4 chunks)
    // B: unit u = wave*64 + lane over 512 units (128 rows x 4 chunks)
    const bf16_t* ga0; const bf16_t* ga1; const bf16_t* gb;
    {
        const int u0 = (wave * 2) * 64 + lane;
        const int r0 = u0 >> 2;
        ga0 = A + (size_t)(m0 + r0) * K + (((u0 & 3) ^ ((r0 ^ (r0 >> 2)) & 3)) * 8);
        const int u1 = (wave * 2 + 1) * 64 + lane;
        const int r1 = u1 >> 2;
        ga1 = A + (size_t)(m0 + r1) * K + (((u1 & 3) ^ ((r1 ^ (r1 >> 2)) & 3)) * 8);
        const int ub = wave * 64 + lane;
        const int rb = ub >> 2;
        gb  = B + (size_t)(n0 + rb) * K + (((ub & 3) ^ ((rb ^ (rb >> 2)) & 3)) * 8);
    }
    const int la0 = wave * 1024;         // elem offsets (unit*8), wave-uniform
    const int la1 = wave * 1024 + 512;
    const int lb  = wave * 512;

#define STAGE(tt, Ad, Bd) do {                                   \
    GLD16(ga0 + (size_t)(tt) * BK, (Ad) + la0);                  \
    GLD16(ga1 + (size_t)(tt) * BK, (Ad) + la1);                  \
    GLD16(gb  + (size_t)(tt) * BK, (Bd) + lb);                   \
} while (0)

    f32x4 acc[4][4];
#pragma unroll
    for (int i = 0; i < 4; ++i)
#pragma unroll
        for (int j = 0; j < 4; ++j) acc[i][j] = (f32x4){0.f, 0.f, 0.f, 0.f};

    // prologue: stage tile 0 -> buf0, tile 1 -> buf1; wait tile0 only.
    STAGE(0, As, Bs);
    STAGE(1, As + ABUF, Bs + BBUF);
    asm volatile("s_waitcnt vmcnt(3)" ::: "memory");   // tile0 landed
    blockbar();

    int bc = 0;                                        // compute buffer = t%3
    for (int t = 0; t < NT; ++t) {
        const bf16_t* __restrict__ Ab = As + bc * ABUF;
        const bf16_t* __restrict__ Bb = Bs + bc * BBUF;
        const int bs2 = (bc >= 1) ? bc - 1 : 2;        // (bc+2)%3
        const bool do_stage = (t + 2 < NT);

        bf16x8 af[4], bfr[4];
#pragma unroll
        for (int i = 0; i < 4; ++i) {
            const int row = wm * 64 + i * 16 + fm;
            af[i] = *(const bf16x8*)(Ab + (size_t)(row * 4 + (q ^ fsw2)) * 8);
        }
#pragma unroll
        for (int j = 0; j < 4; ++j) {
            const int row = wn * 64 + j * 16 + fm;
            bfr[j] = *(const bf16x8*)(Bb + (size_t)(row * 4 + (q ^ fsw2)) * 8);
        }
        if (do_stage) STAGE(t + 2, As + bs2 * ABUF, Bs + bs2 * BBUF);

        __builtin_amdgcn_s_setprio(1);
#pragma unroll
        for (int i = 0; i < 4; ++i)
#pragma unroll
            for (int j = 0; j < 4; ++j)
                acc[i][j] = __builtin_amdgcn_mfma_f32_16x16x32_bf16(
                    af[i], bfr[j], acc[i][j], 0, 0, 0);
        __builtin_amdgcn_s_setprio(0);

        if (t < NT - 1) {
            // own frag reads retired (MFMA consumed them; explicit for safety)
            asm volatile("s_waitcnt lgkmcnt(0)" ::: "memory");
            if (do_stage) asm volatile("s_waitcnt vmcnt(3)" ::: "memory"); // t+1 landed
            else          asm volatile("s_waitcnt vmcnt(0)" ::: "memory"); // drain tail
            blockbar();   // single barrier per K-tile
        }
        bc = (bc >= 2) ? 0 : bc + 1;
    }

    // epilogue: C/D layout col=lane&15, row=q*4+r
#pragma unroll
    for (int i = 0; i < 4; ++i) {
#pragma unroll
        for (int j = 0; j < 4; ++j) {
            const int col = n0 + wn * 64 + j * 16 + fm;
            float bv = 0.f;
            if (EPI == EPI_BIAS) bv = bias[col];
#pragma unroll
            for (int r = 0; r < 4; ++r) {
                const int row = m0 + wm * 64 + i * 16 + q * 4 + r;
                float v = acc[i][j][r];
                if (EPI == EPI_THRESH) v = (fabsf(v) > 1e-3f) ? v : 0.f;
                if (EPI == EPI_BIAS) v += bv;
                C[(size_t)row * N + col] = (CT)v;
            }
        }
    }
#undef STAGE
}

// dispatch 2: blocks 0..17 = Wc = VTb @ Wt^T (front, absorbed by
// co-residency instead of forming a tail round); blocks 18..785 =
// h = thresh(xb @ Ub^T), bijective XCD swizzle over 768 (768%8==0).
__global__ __launch_bounds__(512, 4)
void gemm_h_wc(const bf16_t* __restrict__ xb, const bf16_t* __restrict__ Ub,
               bf16_t* __restrict__ h,
               const bf16_t* __restrict__ VTb, const bf16_t* __restrict__ Wt,
               bf16_t* __restrict__ Wc)
{
    __shared__ __align__(16) bf16_t As[3 * ABUF];   // 48 KiB
    __shared__ __align__(16) bf16_t Bs[3 * BBUF];   // 24 KiB
    const int b = blockIdx.x;
    if (b < 18) {
        gemm_tile<EPI_NONE, bf16_t>(VTb, Wt, Wc, nullptr,
                                    (b / 6) * BM, (b % 6) * BN, 768, 768, As, Bs);
    } else {
        const int bb = b - 18;
        const int L = (bb & 7) * 96 + (bb >> 3);    // XCD-contiguous tiles
        gemm_tile<EPI_THRESH, bf16_t>(xb, Ub, h, nullptr,
                                      (L / 6) * BM, (L % 6) * BN, 768, 768, As, Bs);
    }
}

// dispatch 3: out = h @ Wc^T + bias (fp32 store)
__global__ __launch_bounds__(512, 4)
void gemm_out(const bf16_t* __restrict__ h, const bf16_t* __restrict__ Wc,
              float* __restrict__ out, const float* __restrict__ bias)
{
    __shared__ __align__(16) bf16_t As[3 * ABUF];
    __shared__ __align__(16) bf16_t Bs[3 * BBUF];
    const int b = blockIdx.x;
    const int L = (b & 7) * 96 + (b >> 3);
    gemm_tile<EPI_BIAS, float>(h, Wc, out, bias,
                               (L / 6) * BM, (L % 6) * BN, 768, 768, As, Bs);
}

// dispatch 1: fp32->bf16 conversions + weight transpose (unchanged, ~BW-bound).
// blocks [0,12288): x; [12288,12576): U; [12576,12864): VT; [12864,13440): w^T
__global__ __launch_bounds__(256)
void prep(const float* __restrict__ x, const float* __restrict__ U,
          const float* __restrict__ VT, const float* __restrict__ w,
          bf16_t* __restrict__ xb, bf16_t* __restrict__ Ub,
          bf16_t* __restrict__ VTb, bf16_t* __restrict__ Wt)
{
    __shared__ float tt[32][33];
    const int b = blockIdx.x;
    if (b < 12864) {
        const float* src; bf16_t* dst; size_t e;
        if (b < 12288)      { src = x;  dst = xb;  e = (size_t)b * 2048; }
        else if (b < 12576) { src = U;  dst = Ub;  e = (size_t)(b - 12288) * 2048; }
        else                { src = VT; dst = VTb; e = (size_t)(b - 12576) * 2048; }
        const size_t i = e + (size_t)threadIdx.x * 8;
        const f32x4 v0 = *(const f32x4*)(src + i);
        const f32x4 v1 = *(const f32x4*)(src + i + 4);
        bf16x8 o;
        o[0] = (bf16_t)v0[0]; o[1] = (bf16_t)v0[1];
        o[2] = (bf16_t)v0[2]; o[3] = (bf16_t)v0[3];
        o[4] = (bf16_t)v1[0]; o[5] = (bf16_t)v1[1];
        o[6] = (bf16_t)v1[2]; o[7] = (bf16_t)v1[3];
        *(bf16x8*)(dst + i) = o;
    } else {
        const int t = b - 12864;              // 0..575
        const int bx = (t % 24) * 32, by = (t / 24) * 32;
        const int tx = threadIdx.x & 31, ty = threadIdx.x >> 5;  // 32 x 8
#pragma unroll
        for (int i = 0; i < 32; i += 8)
            tt[ty + i][tx] = w[(size_t)(by + ty + i) * 768 + bx + tx];
        __syncthreads();
#pragma unroll
        for (int i = 0; i < 32; i += 8)
            Wt[(size_t)(bx + ty + i) * 768 + by + tx] = (bf16_t)tt[tx][ty + i];
    }
}

extern "C" void kernel_launch(void* const* d_in, const int* in_sizes, int n_in,
                              void* d_out, int out_size, void* d_ws, size_t ws_size,
                              hipStream_t stream)
{
    const float* x    = (const float*)d_in[0];   // (8,4096,768) fp32
    const float* w    = (const float*)d_in[1];   // (768,768) fp32
    const float* bias = (const float*)d_in[2];   // (768,) fp32
    const float* U    = (const float*)d_in[3];   // (768,768) fp32
    const float* VT   = (const float*)d_in[4];   // (768,768) fp32
    float* out = (float*)d_out;                  // (8,4096,768) fp32

    const int D = 768;
    const int M = 8 * 4096;                      // 32768
    const size_t MD = (size_t)M * D;
    const size_t DD = (size_t)D * D;

    char* ws = (char*)d_ws;
    bf16_t* xb  = (bf16_t*)ws;                         // MD bf16
    bf16_t* h   = (bf16_t*)(ws + MD * 2);              // MD bf16
    bf16_t* Ub  = (bf16_t*)(ws + MD * 4);              // DD
    bf16_t* VTb = (bf16_t*)(ws + MD * 4 + DD * 2);     // DD
    bf16_t* Wt  = (bf16_t*)(ws + MD * 4 + DD * 4);     // DD: weight^T
    bf16_t* Wc  = (bf16_t*)(ws + MD * 4 + DD * 6);     // DD: VT@weight

    // 1) conversions + transpose fused
    prep<<<13440, 256, 0, stream>>>(x, U, VT, w, xb, Ub, VTb, Wt);
    // 2) Wc = (VT @ weight) [first 18 blocks] + h = thresh(xb @ Ub^T)
    gemm_h_wc<<<18 + 768, 512, 0, stream>>>(xb, Ub, h, VTb, Wt, Wc);
    // 3) out = h @ Wc^T + bias  (== ((h @ W^T) @ VT^T) + bias)
    gemm_out<<<768, 512, 0, stream>>>(h, Wc, out, bias);
}